// Round 3
// baseline (95.196 us; speedup 1.0000x reference)
//
#include <hip/hip_runtime.h>

// AnatomicalConsistencyLoss: fused separable-Sobel magnitude + cosine loss.
// pred/target (2,1,160,160,160) f32 -> scalar f32.
// R3: register-prefetch pipeline (issue plane p+1 loads before barrier, consume
// after), double-buffered combo LDS (1 barrier/plane), shfl-based x-halo.

constexpr int Dd = 160, Hh = 160, Ww = 160;
constexpr int TW = 32, TH = 32, DC = 8;
constexpr int NTX = Ww / TW;                 // 5
constexpr int NB_X = NTX * (Hh / TH);        // 25
constexpr int NB_Y = Dd / DC;                // 20
constexpr int NB_Z = 2;
constexpr int NBLOCKS = NB_X * NB_Y * NB_Z;  // 1000
constexpr int PLANES = DC + 2;               // 10
constexpr int PLSZ = Hh * Ww;                // 25600
constexpr double NVOX = 2.0 * Dd * Hh * Ww;  // 8,192,000

__device__ __forceinline__ float4 sm3(const float4 a, const float4 b, const float4 c) {
    return make_float4(a.x + 2.f*b.x + c.x, a.y + 2.f*b.y + c.y,
                       a.z + 2.f*b.z + c.z, a.w + 2.f*b.w + c.w);
}
__device__ __forceinline__ float4 df2(const float4 a, const float4 c) {
    return make_float4(c.x - a.x, c.y - a.y, c.z - a.z, c.w - a.w);
}
__device__ __forceinline__ float4 mul4(const float4 a, const float4 b) {
    return make_float4(a.x*b.x, a.y*b.y, a.z*b.z, a.w*b.w);
}
__device__ __forceinline__ float4 fma4(const float4 a, const float4 b, const float4 c) {
    return make_float4(fmaf(a.x,b.x,c.x), fmaf(a.y,b.y,c.y),
                       fmaf(a.z,b.z,c.z), fmaf(a.w,b.w,c.w));
}
__device__ __forceinline__ float4 sub4(const float4 a, const float4 b) {
    return make_float4(a.x-b.x, a.y-b.y, a.z-b.z, a.w-b.w);
}
__device__ __forceinline__ float4 adds4(const float4 a, const float s) {
    return make_float4(a.x+s, a.y+s, a.z+s, a.w+s);
}
__device__ __forceinline__ float4 maxs4(const float4 a, const float s) {
    return make_float4(fmaxf(a.x,s), fmaxf(a.y,s), fmaxf(a.z,s), fmaxf(a.w,s));
}
__device__ __forceinline__ float4 sqrt4(const float4 a) {
    return make_float4(__builtin_amdgcn_sqrtf(a.x), __builtin_amdgcn_sqrtf(a.y),
                       __builtin_amdgcn_sqrtf(a.z), __builtin_amdgcn_sqrtf(a.w));
}
__device__ __forceinline__ float4 rsq4(const float4 a) {
    return make_float4(__builtin_amdgcn_rsqf(a.x), __builtin_amdgcn_rsqf(a.y),
                       __builtin_amdgcn_rsqf(a.z), __builtin_amdgcn_rsqf(a.w));
}

__global__ __launch_bounds__(256, 4)
void acl_partial(const float* __restrict__ pred, const float* __restrict__ targ,
                 float2* __restrict__ partial)
{
    // [zbuf][vol][row][xgrp], row stride 128B (b128 quarter-wave phases are
    // 256B-contiguous -> conflict-free, verified 0 conflicts in R2)
    __shared__ float4 sHS[2][2][TH + 2][8];
    __shared__ float4 sHD[2][2][TH + 2][8];
    __shared__ float rred[8];

    const int tid = threadIdx.x;
    const int gx = tid & 7;          // x-group of 4 floats
    const int r  = tid >> 3;         // row 0..31

    const int wt = blockIdx.x % NTX;
    const int ht = blockIdx.x / NTX;
    const int x0 = wt * TW, y0 = ht * TH;
    const int z0 = blockIdx.y * DC;
    const size_t base = (size_t)blockIdx.z * ((size_t)Dd * PLSZ);
    const float* __restrict__ pv = pred + base;
    const float* __restrict__ tv = targ + base;

    const int xA = x0 + gx * 4;
    const bool eLo = (gx == 0);
    const bool eHi = (gx == 7);
    const bool xm  = (x0 > 0);
    const bool xp  = (x0 + TW < Ww);

    const int yA1  = y0 - 1 + r;
    const bool yok1 = (unsigned)yA1 < (unsigned)Hh;
    const int ro1  = yA1 * Ww + xA;

    const bool has2 = (tid < 16);
    const int r2   = TH + (tid >> 3);              // 32 / 33 (for tid<16)
    const int yA2  = y0 - 1 + r2;
    const bool yok2 = has2 && ((unsigned)yA2 < (unsigned)Hh);
    const int ro2  = yA2 * Ww + xA;

    // ---- prefetch registers (one plane in flight) ----
    float4 vp1, vt1, vp2, vt2;
    float eap1, ebp1, eat1, ebt1, eap2, ebp2, eat2, ebt2;

    auto issue = [&](int p) {
        const int gz = z0 - 1 + p;
        const bool zok = (unsigned)gz < (unsigned)Dd;   // wave-uniform
        const float* pz = pv + (ptrdiff_t)gz * PLSZ;
        const float* tz = tv + (ptrdiff_t)gz * PLSZ;
        vp1 = vt1 = vp2 = vt2 = make_float4(0.f, 0.f, 0.f, 0.f);
        eap1 = ebp1 = eat1 = ebt1 = 0.f;
        eap2 = ebp2 = eat2 = ebt2 = 0.f;
        if (zok) {
            if (yok1) {
                vp1 = *(const float4*)(pz + ro1);
                vt1 = *(const float4*)(tz + ro1);
                if (eLo && xm) { eap1 = pz[ro1 - 1]; eat1 = tz[ro1 - 1]; }
                if (eHi && xp) { ebp1 = pz[ro1 + 4]; ebt1 = tz[ro1 + 4]; }
            }
            if (yok2) {
                vp2 = *(const float4*)(pz + ro2);
                vt2 = *(const float4*)(tz + ro2);
                if (eLo && xm) { eap2 = pz[ro2 - 1]; eat2 = tz[ro2 - 1]; }
                if (eHi && xp) { ebp2 = pz[ro2 + 4]; ebt2 = tz[ro2 + 4]; }
            }
        }
    };

    // horizontal combos; x-halo from neighbor lanes via shfl (edge lanes use
    // the scalar-loaded value). All lanes execute (shfl uniformity).
    auto combo = [&](const float4 v, const float elo, const float ehi,
                     float4& HS, float4& HD) {
        float e0 = __shfl_up(v.w, 1);
        if (eLo) e0 = elo;
        float e5 = __shfl_down(v.x, 1);
        if (eHi) e5 = ehi;
        HS = make_float4(e0 + 2.f*v.x + v.y,
                         v.x + 2.f*v.y + v.z,
                         v.y + 2.f*v.z + v.w,
                         v.z + 2.f*v.w + e5);
        HD = make_float4(v.y - e0, v.z - v.x, v.w - v.y, e5 - v.z);
    };

    float4 Ap[3], Bp[3], Cp[3], At[3], Bt[3], Ct[3];
    float4 accm = make_float4(0.f,0.f,0.f,0.f);
    float4 accc = make_float4(0.f,0.f,0.f,0.f);

    issue(0);

    #pragma unroll
    for (int p = 0; p < PLANES; ++p) {
        const int buf = p & 1;

        // ---- consume prefetched regs -> combos -> LDS buf[p&1] ----
        {
            float4 hs, hd;
            combo(vp1, eap1, ebp1, hs, hd);
            sHS[buf][0][r][gx] = hs;  sHD[buf][0][r][gx] = hd;
            combo(vt1, eat1, ebt1, hs, hd);
            sHS[buf][1][r][gx] = hs;  sHD[buf][1][r][gx] = hd;

            float4 hsp2, hdp2, hst2, hdt2;
            combo(vp2, eap2, ebp2, hsp2, hdp2);
            combo(vt2, eat2, ebt2, hst2, hdt2);
            if (has2) {
                sHS[buf][0][r2][gx] = hsp2;  sHD[buf][0][r2][gx] = hdp2;
                sHS[buf][1][r2][gx] = hst2;  sHD[buf][1][r2][gx] = hdt2;
            }
        }

        // ---- issue next plane's loads (fly across the barrier, T14) ----
        if (p + 1 < PLANES) issue(p + 1);

        __syncthreads();

        // ---- stage B: vertical combine into z-ring ----
        const int s2i = p % 3;   // static after full unroll
        {
            const float4 h0 = sHS[buf][0][r][gx], h1 = sHS[buf][0][r+1][gx], h2 = sHS[buf][0][r+2][gx];
            const float4 d0 = sHD[buf][0][r][gx], d1 = sHD[buf][0][r+1][gx], d2 = sHD[buf][0][r+2][gx];
            Ap[s2i] = sm3(h0, h1, h2);
            Cp[s2i] = df2(h0, h2);
            Bp[s2i] = sm3(d0, d1, d2);
        }
        {
            const float4 h0 = sHS[buf][1][r][gx], h1 = sHS[buf][1][r+1][gx], h2 = sHS[buf][1][r+2][gx];
            const float4 d0 = sHD[buf][1][r][gx], d1 = sHD[buf][1][r+1][gx], d2 = sHD[buf][1][r+2][gx];
            At[s2i] = sm3(h0, h1, h2);
            Ct[s2i] = df2(h0, h2);
            Bt[s2i] = sm3(d0, d1, d2);
        }

        if (p >= 2) {
            const int s0 = (p - 2) % 3, s1 = (p - 1) % 3, s2 = p % 3;
            const float4 gxp = sm3(Bp[s0], Bp[s1], Bp[s2]);
            const float4 gyp = sm3(Cp[s0], Cp[s1], Cp[s2]);
            const float4 gzp = df2(Ap[s0], Ap[s2]);
            const float4 gxt = sm3(Bt[s0], Bt[s1], Bt[s2]);
            const float4 gyt = sm3(Ct[s0], Ct[s1], Ct[s2]);
            const float4 gzt = df2(At[s0], At[s2]);

            const float4 np2 = fma4(gxp, gxp, fma4(gyp, gyp, mul4(gzp, gzp)));
            const float4 nt2 = fma4(gxt, gxt, fma4(gyt, gyt, mul4(gzt, gzt)));

            const float4 pm = sqrt4(adds4(np2, 1e-8f));
            const float4 tm = sqrt4(adds4(nt2, 1e-8f));
            const float4 dm = sub4(pm, tm);
            accm = fma4(dm, dm, accm);

            const float4 dot = fma4(gxp, gxt, fma4(gyp, gyt, mul4(gzp, gzt)));
            const float4 ra = rsq4(maxs4(np2, 1e-30f));
            const float4 rb = rsq4(maxs4(nt2, 1e-30f));
            accc = fma4(mul4(dot, ra), rb, accc);
        }
        // no trailing barrier: next plane writes the OTHER buffer; the single
        // per-plane barrier two iterations apart protects buffer reuse.
    }

    // ---- block reduction ----
    float am = accm.x + accm.y + accm.z + accm.w;
    float ac = accc.x + accc.y + accc.z + accc.w;
    #pragma unroll
    for (int off = 32; off >= 1; off >>= 1) {
        am += __shfl_down(am, off);
        ac += __shfl_down(ac, off);
    }
    const int wid = tid >> 6;
    if ((tid & 63) == 0) { rred[wid] = am; rred[4 + wid] = ac; }
    __syncthreads();
    if (tid == 0) {
        const float m = rred[0] + rred[1] + rred[2] + rred[3];
        const float c = rred[4] + rred[5] + rred[6] + rred[7];
        const int bid = (blockIdx.z * gridDim.y + blockIdx.y) * gridDim.x + blockIdx.x;
        partial[bid] = make_float2(m, c);
    }
}

__global__ __launch_bounds__(256)
void acl_final(const float2* __restrict__ partial, float* __restrict__ out)
{
    __shared__ double sm[256], sc[256];
    double m = 0.0, c = 0.0;
    for (int i = threadIdx.x; i < NBLOCKS; i += 256) {
        const float2 v = partial[i];
        m += (double)v.x;
        c += (double)v.y;
    }
    sm[threadIdx.x] = m;
    sc[threadIdx.x] = c;
    __syncthreads();
    #pragma unroll
    for (int s = 128; s >= 1; s >>= 1) {
        if (threadIdx.x < (unsigned)s) {
            sm[threadIdx.x] += sm[threadIdx.x + s];
            sc[threadIdx.x] += sc[threadIdx.x + s];
        }
        __syncthreads();
    }
    if (threadIdx.x == 0) {
        const double mag_loss = sm[0] / NVOX;
        const double dir_loss = 1.0 - sc[0] / NVOX;
        out[0] = (float)(0.2 * (mag_loss + dir_loss));
    }
}

extern "C" void kernel_launch(void* const* d_in, const int* in_sizes, int n_in,
                              void* d_out, int out_size, void* d_ws, size_t ws_size,
                              hipStream_t stream) {
    const float* pred = (const float*)d_in[0];
    const float* targ = (const float*)d_in[1];
    float* out = (float*)d_out;
    float2* partial = (float2*)d_ws;  // 1000 * 8 B = 8 KB

    dim3 grid(NB_X, NB_Y, NB_Z);  // (25, 20, 2)
    acl_partial<<<grid, 256, 0, stream>>>(pred, targ, partial);
    acl_final<<<1, 256, 0, stream>>>(partial, out);
}

// Round 4
// 55.987 us; speedup vs baseline: 1.7003x; 1.7003x over previous
//
#include <hip/hip_runtime.h>

// AnatomicalConsistencyLoss: fused separable-Sobel magnitude + cosine loss.
// pred/target (2,1,160,160,160) f32 -> scalar f32.
// R4: R3's register-prefetch pipeline, but with GUARANTEED-static ring indices
// (explicit per-plane template unroll via IC<P>) and launch_bounds(256,3)
// (VGPR cap ~170) so nothing spills to scratch. One barrier per plane,
// double-buffered combo LDS, shfl x-halo.

constexpr int Dd = 160, Hh = 160, Ww = 160;
constexpr int TW = 32, TH = 32, DC = 8;
constexpr int NTX = Ww / TW;                 // 5
constexpr int NB_X = NTX * (Hh / TH);        // 25
constexpr int NB_Y = Dd / DC;                // 20
constexpr int NB_Z = 2;
constexpr int NBLOCKS = NB_X * NB_Y * NB_Z;  // 1000
constexpr int PLANES = DC + 2;               // 10
constexpr int PLSZ = Hh * Ww;                // 25600
constexpr double NVOX = 2.0 * Dd * Hh * Ww;  // 8,192,000

template <int N> struct IC { static constexpr int value = N; };

__device__ __forceinline__ float4 sm3(const float4 a, const float4 b, const float4 c) {
    return make_float4(a.x + 2.f*b.x + c.x, a.y + 2.f*b.y + c.y,
                       a.z + 2.f*b.z + c.z, a.w + 2.f*b.w + c.w);
}
__device__ __forceinline__ float4 df2(const float4 a, const float4 c) {
    return make_float4(c.x - a.x, c.y - a.y, c.z - a.z, c.w - a.w);
}
__device__ __forceinline__ float4 mul4(const float4 a, const float4 b) {
    return make_float4(a.x*b.x, a.y*b.y, a.z*b.z, a.w*b.w);
}
__device__ __forceinline__ float4 fma4(const float4 a, const float4 b, const float4 c) {
    return make_float4(fmaf(a.x,b.x,c.x), fmaf(a.y,b.y,c.y),
                       fmaf(a.z,b.z,c.z), fmaf(a.w,b.w,c.w));
}
__device__ __forceinline__ float4 sub4(const float4 a, const float4 b) {
    return make_float4(a.x-b.x, a.y-b.y, a.z-b.z, a.w-b.w);
}
__device__ __forceinline__ float4 adds4(const float4 a, const float s) {
    return make_float4(a.x+s, a.y+s, a.z+s, a.w+s);
}
__device__ __forceinline__ float4 maxs4(const float4 a, const float s) {
    return make_float4(fmaxf(a.x,s), fmaxf(a.y,s), fmaxf(a.z,s), fmaxf(a.w,s));
}
__device__ __forceinline__ float4 sqrt4(const float4 a) {
    return make_float4(__builtin_amdgcn_sqrtf(a.x), __builtin_amdgcn_sqrtf(a.y),
                       __builtin_amdgcn_sqrtf(a.z), __builtin_amdgcn_sqrtf(a.w));
}
__device__ __forceinline__ float4 rsq4(const float4 a) {
    return make_float4(__builtin_amdgcn_rsqf(a.x), __builtin_amdgcn_rsqf(a.y),
                       __builtin_amdgcn_rsqf(a.z), __builtin_amdgcn_rsqf(a.w));
}

__global__ __launch_bounds__(256, 3)
void acl_partial(const float* __restrict__ pred, const float* __restrict__ targ,
                 float2* __restrict__ partial)
{
    // [zbuf][vol][row][xgrp] float4; row stride 128B (0 conflicts measured)
    __shared__ float4 sHS[2][2][TH + 2][8];
    __shared__ float4 sHD[2][2][TH + 2][8];
    __shared__ float rred[8];

    const int tid = threadIdx.x;
    const int gx = tid & 7;          // x-group of 4 floats
    const int r  = tid >> 3;         // row 0..31

    const int wt = blockIdx.x % NTX;
    const int ht = blockIdx.x / NTX;
    const int x0 = wt * TW, y0 = ht * TH;
    const int z0 = blockIdx.y * DC;
    const size_t base = (size_t)blockIdx.z * ((size_t)Dd * PLSZ);
    const float* __restrict__ pv = pred + base;
    const float* __restrict__ tv = targ + base;

    const int xA = x0 + gx * 4;
    const bool eLo = (gx == 0);
    const bool eHi = (gx == 7);
    const bool xm  = (x0 > 0);
    const bool xp  = (x0 + TW < Ww);

    const int yA1  = y0 - 1 + r;
    const bool yok1 = (unsigned)yA1 < (unsigned)Hh;
    const int ro1  = yA1 * Ww + xA;

    const bool has2 = (tid < 16);
    const int r2   = TH + (tid >> 3);              // 32 / 33 (for tid<16)
    const int yA2  = y0 - 1 + r2;
    const bool yok2 = has2 && ((unsigned)yA2 < (unsigned)Hh);
    const int ro2  = yA2 * Ww + xA;

    // ---- prefetch registers (one plane in flight) ----
    float4 vp1, vt1, vp2, vt2;
    float eap1, ebp1, eat1, ebt1, eap2, ebp2, eat2, ebt2;

    auto issue = [&](int p) {
        const int gz = z0 - 1 + p;
        const bool zok = (unsigned)gz < (unsigned)Dd;   // wave-uniform
        const float* pz = pv + (ptrdiff_t)gz * PLSZ;
        const float* tz = tv + (ptrdiff_t)gz * PLSZ;
        vp1 = vt1 = vp2 = vt2 = make_float4(0.f, 0.f, 0.f, 0.f);
        eap1 = ebp1 = eat1 = ebt1 = 0.f;
        eap2 = ebp2 = eat2 = ebt2 = 0.f;
        if (zok) {
            if (yok1) {
                vp1 = *(const float4*)(pz + ro1);
                vt1 = *(const float4*)(tz + ro1);
                if (eLo && xm) { eap1 = pz[ro1 - 1]; eat1 = tz[ro1 - 1]; }
                if (eHi && xp) { ebp1 = pz[ro1 + 4]; ebt1 = tz[ro1 + 4]; }
            }
            if (yok2) {
                vp2 = *(const float4*)(pz + ro2);
                vt2 = *(const float4*)(tz + ro2);
                if (eLo && xm) { eap2 = pz[ro2 - 1]; eat2 = tz[ro2 - 1]; }
                if (eHi && xp) { ebp2 = pz[ro2 + 4]; ebt2 = tz[ro2 + 4]; }
            }
        }
    };

    // horizontal combos; x-halo via shfl from neighbor lanes (edge lanes use
    // their prefetched scalar). All lanes execute (shfl uniformity).
    auto combo = [&](const float4 v, const float elo, const float ehi,
                     float4& HS, float4& HD) {
        float e0 = __shfl_up(v.w, 1);
        if (eLo) e0 = elo;
        float e5 = __shfl_down(v.x, 1);
        if (eHi) e5 = ehi;
        HS = make_float4(e0 + 2.f*v.x + v.y,
                         v.x + 2.f*v.y + v.z,
                         v.y + 2.f*v.z + v.w,
                         v.z + 2.f*v.w + e5);
        HD = make_float4(v.y - e0, v.z - v.x, v.w - v.y, e5 - v.z);
    };

    float4 Ap[3], Bp[3], Cp[3], At[3], Bt[3], Ct[3];
    float4 accm = make_float4(0.f,0.f,0.f,0.f);
    float4 accc = make_float4(0.f,0.f,0.f,0.f);

    issue(0);

    // One plane-step; P is a compile-time constant so all ring indices are
    // static (registers guaranteed, rule #20) and buffer parity is static.
    auto step = [&](auto Pc) {
        constexpr int P   = decltype(Pc)::value;
        constexpr int BUF = P & 1;
        constexpr int S2  = P % 3;

        // ---- consume prefetched regs -> combos -> LDS[BUF] ----
        {
            float4 hs, hd;
            combo(vp1, eap1, ebp1, hs, hd);
            sHS[BUF][0][r][gx] = hs;  sHD[BUF][0][r][gx] = hd;
            combo(vt1, eat1, ebt1, hs, hd);
            sHS[BUF][1][r][gx] = hs;  sHD[BUF][1][r][gx] = hd;

            float4 hp2, dp2, ht2, dt2;
            combo(vp2, eap2, ebp2, hp2, dp2);
            combo(vt2, eat2, ebt2, ht2, dt2);
            if (has2) {
                sHS[BUF][0][r2][gx] = hp2;  sHD[BUF][0][r2][gx] = dp2;
                sHS[BUF][1][r2][gx] = ht2;  sHD[BUF][1][r2][gx] = dt2;
            }
        }

        // ---- issue next plane's loads; they fly across the barrier ----
        if constexpr (P + 1 < PLANES) { issue(P + 1); }

        __syncthreads();

        // ---- vertical combine into ring slot S2 (static) ----
        {
            const float4 h0 = sHS[BUF][0][r][gx], h1 = sHS[BUF][0][r+1][gx], h2 = sHS[BUF][0][r+2][gx];
            const float4 d0 = sHD[BUF][0][r][gx], d1 = sHD[BUF][0][r+1][gx], d2 = sHD[BUF][0][r+2][gx];
            Ap[S2] = sm3(h0, h1, h2);
            Cp[S2] = df2(h0, h2);
            Bp[S2] = sm3(d0, d1, d2);
        }
        {
            const float4 h0 = sHS[BUF][1][r][gx], h1 = sHS[BUF][1][r+1][gx], h2 = sHS[BUF][1][r+2][gx];
            const float4 d0 = sHD[BUF][1][r][gx], d1 = sHD[BUF][1][r+1][gx], d2 = sHD[BUF][1][r+2][gx];
            At[S2] = sm3(h0, h1, h2);
            Ct[S2] = df2(h0, h2);
            Bt[S2] = sm3(d0, d1, d2);
        }

        if constexpr (P >= 2) {
            constexpr int S0 = (P - 2) % 3, S1 = (P - 1) % 3;
            const float4 gxp = sm3(Bp[S0], Bp[S1], Bp[S2]);
            const float4 gyp = sm3(Cp[S0], Cp[S1], Cp[S2]);
            const float4 gzp = df2(Ap[S0], Ap[S2]);
            const float4 gxt = sm3(Bt[S0], Bt[S1], Bt[S2]);
            const float4 gyt = sm3(Ct[S0], Ct[S1], Ct[S2]);
            const float4 gzt = df2(At[S0], At[S2]);

            const float4 np2 = fma4(gxp, gxp, fma4(gyp, gyp, mul4(gzp, gzp)));
            const float4 nt2 = fma4(gxt, gxt, fma4(gyt, gyt, mul4(gzt, gzt)));

            const float4 pm = sqrt4(adds4(np2, 1e-8f));
            const float4 tm = sqrt4(adds4(nt2, 1e-8f));
            const float4 dm = sub4(pm, tm);
            accm = fma4(dm, dm, accm);

            // dot/(||gp||*||gt||); eps guards unreachable for nonzero grads,
            // and dot==0 whenever a gradient is exactly 0.
            const float4 dot = fma4(gxp, gxt, fma4(gyp, gyt, mul4(gzp, gzt)));
            const float4 ra = rsq4(maxs4(np2, 1e-30f));
            const float4 rb = rsq4(maxs4(nt2, 1e-30f));
            accc = fma4(mul4(dot, ra), rb, accc);
        }
        // no trailing barrier: next step writes the OTHER buffer; this step's
        // barrier already orders buffer reuse two steps apart.
    };

    step(IC<0>{}); step(IC<1>{}); step(IC<2>{}); step(IC<3>{}); step(IC<4>{});
    step(IC<5>{}); step(IC<6>{}); step(IC<7>{}); step(IC<8>{}); step(IC<9>{});

    // ---- block reduction ----
    float am = accm.x + accm.y + accm.z + accm.w;
    float ac = accc.x + accc.y + accc.z + accc.w;
    #pragma unroll
    for (int off = 32; off >= 1; off >>= 1) {
        am += __shfl_down(am, off);
        ac += __shfl_down(ac, off);
    }
    const int wid = tid >> 6;
    if ((tid & 63) == 0) { rred[wid] = am; rred[4 + wid] = ac; }
    __syncthreads();
    if (tid == 0) {
        const float m = rred[0] + rred[1] + rred[2] + rred[3];
        const float c = rred[4] + rred[5] + rred[6] + rred[7];
        const int bid = (blockIdx.z * gridDim.y + blockIdx.y) * gridDim.x + blockIdx.x;
        partial[bid] = make_float2(m, c);
    }
}

__global__ __launch_bounds__(256)
void acl_final(const float2* __restrict__ partial, float* __restrict__ out)
{
    __shared__ double sm[256], sc[256];
    double m = 0.0, c = 0.0;
    for (int i = threadIdx.x; i < NBLOCKS; i += 256) {
        const float2 v = partial[i];
        m += (double)v.x;
        c += (double)v.y;
    }
    sm[threadIdx.x] = m;
    sc[threadIdx.x] = c;
    __syncthreads();
    #pragma unroll
    for (int s = 128; s >= 1; s >>= 1) {
        if (threadIdx.x < (unsigned)s) {
            sm[threadIdx.x] += sm[threadIdx.x + s];
            sc[threadIdx.x] += sc[threadIdx.x + s];
        }
        __syncthreads();
    }
    if (threadIdx.x == 0) {
        const double mag_loss = sm[0] / NVOX;
        const double dir_loss = 1.0 - sc[0] / NVOX;
        out[0] = (float)(0.2 * (mag_loss + dir_loss));
    }
}

extern "C" void kernel_launch(void* const* d_in, const int* in_sizes, int n_in,
                              void* d_out, int out_size, void* d_ws, size_t ws_size,
                              hipStream_t stream) {
    const float* pred = (const float*)d_in[0];
    const float* targ = (const float*)d_in[1];
    float* out = (float*)d_out;
    float2* partial = (float2*)d_ws;  // 1000 * 8 B = 8 KB

    dim3 grid(NB_X, NB_Y, NB_Z);  // (25, 20, 2)
    acl_partial<<<grid, 256, 0, stream>>>(pred, targ, partial);
    acl_final<<<1, 256, 0, stream>>>(partial, out);
}